// Round 4
// baseline (348.196 us; speedup 1.0000x reference)
//
#include <hip/hip_runtime.h>
#include <cstddef>

#define NB_HEAD 16
#define HEAD_DIM 64
#define D_MODEL 1024
#define BATCH 2
#define SEQ 2048
#define MROWS (BATCH * SEQ)  // 4096

typedef __bf16 bf16x8 __attribute__((ext_vector_type(8)));
typedef __bf16 bf16x4 __attribute__((ext_vector_type(4)));
typedef float  f32x4  __attribute__((ext_vector_type(4)));

#define XELEMS ((size_t)MROWS * D_MODEL)     // 4M per z
#define WELEMS ((size_t)D_MODEL * D_MODEL)   // 1M per z

static __device__ __forceinline__ void split_bf16(float x, __bf16& h, __bf16& l) {
    h = (__bf16)x;
    l = (__bf16)(x - (float)h);
}

// ---------------------------------------------------------------------------
// X [4096][1024] fp32 -> Xhi/Xlo bf16 (row-major), per z. Mask-aware: rows in
// 128-strips that proj will skip are not converted.
// ---------------------------------------------------------------------------
__global__ __launch_bounds__(256) void conv_x_kernel(
    const float* __restrict__ X0, const float* __restrict__ X1,
    const float* __restrict__ X2,
    const int* __restrict__ q_len, const int* __restrict__ v_len,
    __bf16* __restrict__ xhi, __bf16* __restrict__ xlo)
{
    const int z = blockIdx.y;
    const size_t base = (size_t)blockIdx.x * 2048 + threadIdx.x * 8;
    const int l  = (int)(base >> 10);        // global row 0..4095
    const int bb = l >> 11;
    const int lb = l & (SEQ - 1);
    const int qlen = q_len[bb], vlen = v_len[bb];
    int need = (z == 0) ? ((qlen + 127) & ~127) : ((vlen + 63) & ~63);
    need = (need + 127) & ~127;              // proj strips are 128-wide
    if (lb >= need) return;

    const float* X = (z == 0) ? X0 : ((z == 1) ? X1 : X2);
    const float4 v0 = *(const float4*)(X + base);
    const float4 v1 = *(const float4*)(X + base + 4);
    const float xs[8] = {v0.x, v0.y, v0.z, v0.w, v1.x, v1.y, v1.z, v1.w};
    bf16x8 h8, l8;
    #pragma unroll
    for (int u = 0; u < 8; ++u) { __bf16 h_, l_; split_bf16(xs[u], h_, l_); h8[u] = h_; l8[u] = l_; }
    *(bf16x8*)(xhi + z * XELEMS + base) = h8;
    *(bf16x8*)(xlo + z * XELEMS + base) = l8;
}

// ---------------------------------------------------------------------------
// W[K][N] fp32 -> Wt_hi[N][K], Wt_lo[N][K] bf16 split, per z in {Q,K,V}.
// ---------------------------------------------------------------------------
__global__ __launch_bounds__(256) void conv_wt_kernel(
    const float* __restrict__ W0, const float* __restrict__ W1,
    const float* __restrict__ W2,
    __bf16* __restrict__ hi, __bf16* __restrict__ lo)
{
    __shared__ float tile[64][65];
    const int t  = threadIdx.x;
    const int k0 = blockIdx.x * 64;
    const int n0 = blockIdx.y * 64;
    const int z  = blockIdx.z;
    const float* W = (z == 0) ? W0 : ((z == 1) ? W1 : W2);
    __bf16* hz = hi + (size_t)z * WELEMS;
    __bf16* lz = lo + (size_t)z * WELEMS;

    #pragma unroll
    for (int p = 0; p < 4; ++p) {
        const int e = (p * 256 + t) * 4;
        const int r = e >> 6, c = e & 63;
        const float4 v = *(const float4*)(W + (size_t)(k0 + r) * D_MODEL + n0 + c);
        tile[r][c] = v.x; tile[r][c + 1] = v.y; tile[r][c + 2] = v.z; tile[r][c + 3] = v.w;
    }
    __syncthreads();
    #pragma unroll
    for (int p = 0; p < 4; ++p) {
        const int e = (p * 256 + t) * 4;
        const int n = e >> 6, kc = e & 63;
        __bf16 h[4], l[4];
        #pragma unroll
        for (int u = 0; u < 4; ++u) split_bf16(tile[kc + u][n], h[u], l[u]);
        *(bf16x4*)(hz + (size_t)(n0 + n) * D_MODEL + k0 + kc) = (bf16x4){h[0], h[1], h[2], h[3]};
        *(bf16x4*)(lz + (size_t)(n0 + n) * D_MODEL + k0 + kc) = (bf16x4){l[0], l[1], l[2], l[3]};
    }
}

// ---------------------------------------------------------------------------
// Split-bf16 MFMA projection v2. C = Xh Wh + Xh Wl + Xl Wh.
// 128x128 tile, BK=32, 4 waves. A and B both async-staged from pre-split bf16
// in FRAGMENT ORDER: sub-tile s (16 rows x 32 k) occupies 1 KB at lane*16 —
// frag reads are contiguous ds_read_b128, zero bank conflicts, no addr math.
// Masked strips skipped. z=2 writes V^T directly.
// ---------------------------------------------------------------------------
__global__ __launch_bounds__(256) void proj_mfma_kernel(
    const __bf16* __restrict__ Xhi, const __bf16* __restrict__ Xlo,
    const __bf16* __restrict__ Wthi, const __bf16* __restrict__ Wtlo,
    const int* __restrict__ q_len, const int* __restrict__ v_len,
    __bf16* __restrict__ qhi, __bf16* __restrict__ qlo,
    __bf16* __restrict__ khi, __bf16* __restrict__ klo,
    __bf16* __restrict__ vthi, __bf16* __restrict__ vtlo)
{
    __shared__ __align__(16) __bf16 Ahi[128 * 32], Alo[128 * 32];
    __shared__ __align__(16) __bf16 Bhi[128 * 32], Blo[128 * 32];

    const int t    = threadIdx.x;
    const int wave = t >> 6, lane = t & 63;
    const int li   = lane & 15, grp = lane >> 4;
    const int wm   = wave >> 1, wn = wave & 1;
    const int n0   = blockIdx.x * 128;
    const int m0   = blockIdx.y * 128;
    const int z    = blockIdx.z;
    const int bb   = m0 >> 11;
    const int l0   = m0 & (SEQ - 1);
    const int qlen = q_len[bb], vlen = v_len[bb];
    const int need = (z == 0) ? ((qlen + 127) & ~127) : ((vlen + 63) & ~63);
    if (l0 >= need) return;   // consumers never read this strip

    const __bf16* Xh = Xhi + z * XELEMS;
    const __bf16* Xl = Xlo + z * XELEMS;
    const __bf16* Wh = Wthi + z * WELEMS;
    const __bf16* Wl = Wtlo + z * WELEMS;

    f32x4 acc[4][4] = {};

    // staging: wave `wave` deposits sub-tiles s = wave and wave+4 of each array
    // source row = (tile_row0 + s*16 + li), col = k0 + grp*8; dst = s*512 + lane*8
    for (int k0 = 0; k0 < D_MODEL; k0 += 32) {
        #pragma unroll
        for (int p = 0; p < 2; ++p) {
            const int s = wave + p * 4;
            const size_t ga = (size_t)(m0 + s * 16 + li) * D_MODEL + k0 + grp * 8;
            const size_t gb = (size_t)(n0 + s * 16 + li) * D_MODEL + k0 + grp * 8;
            const int dst = s * 512 + lane * 8;
            __builtin_amdgcn_global_load_lds(
                (const __attribute__((address_space(1))) void*)(Xh + ga),
                (__attribute__((address_space(3))) void*)&Ahi[dst], 16, 0, 0);
            __builtin_amdgcn_global_load_lds(
                (const __attribute__((address_space(1))) void*)(Xl + ga),
                (__attribute__((address_space(3))) void*)&Alo[dst], 16, 0, 0);
            __builtin_amdgcn_global_load_lds(
                (const __attribute__((address_space(1))) void*)(Wh + gb),
                (__attribute__((address_space(3))) void*)&Bhi[dst], 16, 0, 0);
            __builtin_amdgcn_global_load_lds(
                (const __attribute__((address_space(1))) void*)(Wl + gb),
                (__attribute__((address_space(3))) void*)&Blo[dst], 16, 0, 0);
        }
        __syncthreads();   // drains vmcnt then barrier

        bf16x8 ah[4], al[4];
        #pragma unroll
        for (int i = 0; i < 4; ++i) {
            const int off = (wm * 4 + i) * 512 + lane * 8;
            ah[i] = *(const bf16x8*)&Ahi[off];
            al[i] = *(const bf16x8*)&Alo[off];
        }
        #pragma unroll
        for (int j = 0; j < 4; ++j) {
            const int off = (wn * 4 + j) * 512 + lane * 8;
            const bf16x8 bh = *(const bf16x8*)&Bhi[off];
            const bf16x8 bl = *(const bf16x8*)&Blo[off];
            #pragma unroll
            for (int i = 0; i < 4; ++i) {
                acc[i][j] = __builtin_amdgcn_mfma_f32_16x16x32_bf16(ah[i], bh, acc[i][j], 0, 0, 0);
                acc[i][j] = __builtin_amdgcn_mfma_f32_16x16x32_bf16(ah[i], bl, acc[i][j], 0, 0, 0);
                acc[i][j] = __builtin_amdgcn_mfma_f32_16x16x32_bf16(al[i], bh, acc[i][j], 0, 0, 0);
            }
        }
        __syncthreads();   // all reads done before next staging overwrite
    }

    // Epilogue. C/D layout: col = li, row = grp*4 + r (within each 16x16 tile).
    if (z < 2) {
        __bf16* oh = (z == 0) ? qhi : khi;
        __bf16* ol = (z == 0) ? qlo : klo;
        #pragma unroll
        for (int j = 0; j < 4; ++j) {
            const int cg = n0 + wn * 64 + j * 16 + li;
            const int hd = cg >> 6, d = cg & 63;
            #pragma unroll
            for (int i = 0; i < 4; ++i) {
                #pragma unroll
                for (int r = 0; r < 4; ++r) {
                    const int rg = m0 + wm * 64 + i * 16 + grp * 4 + r;
                    const int lg = rg & (SEQ - 1);
                    const size_t a = (((size_t)bb * NB_HEAD + hd) * SEQ + lg) * HEAD_DIM + d;
                    __bf16 h_, l_;
                    split_bf16(acc[i][j][r], h_, l_);
                    oh[a] = h_; ol[a] = l_;
                }
            }
        }
    } else {
        // V^T [bh][d][SEQ]: pack 4 consecutive l per store
        #pragma unroll
        for (int j = 0; j < 4; ++j) {
            const int cg = n0 + wn * 64 + j * 16 + li;
            const int hd = cg >> 6, d = cg & 63;
            const size_t rowbase = ((size_t)(bb * NB_HEAD + hd) * HEAD_DIM + d) * SEQ;
            #pragma unroll
            for (int i = 0; i < 4; ++i) {
                const int lbase = l0 + wm * 64 + i * 16 + grp * 4;
                bf16x4 ph, pl;
                #pragma unroll
                for (int r = 0; r < 4; ++r) {
                    __bf16 h_, l_;
                    split_bf16(acc[i][j][r], h_, l_);
                    ph[r] = h_; pl[r] = l_;
                }
                *(bf16x4*)(vthi + rowbase + lbase) = ph;
                *(bf16x4*)(vtlo + rowbase + lbase) = pl;
            }
        }
    }
}

// ---------------------------------------------------------------------------
// MFMA flash attention (unchanged from round 3).
// ---------------------------------------------------------------------------
__global__ __launch_bounds__(256) void attn_mfma_kernel(
    const __bf16* __restrict__ qhi, const __bf16* __restrict__ qlo,
    const __bf16* __restrict__ khi, const __bf16* __restrict__ klo,
    const __bf16* __restrict__ vthi, const __bf16* __restrict__ vtlo,
    const int* __restrict__ q_len, const int* __restrict__ v_len,
    float* __restrict__ out)
{
    __shared__ __align__(16) __bf16 Khi[64 * 64], Klo[64 * 64];
    __shared__ __align__(16) __bf16 Vhi[64 * 64], Vlo[64 * 64];
    __shared__ __align__(16) __bf16 Ps[128][72];

    const int t = threadIdx.x;
    const int wq = t >> 6, lane = t & 63;
    const int grp = lane >> 4, li = lane & 15;
    const int q0 = blockIdx.x * 128;
    const int hh = blockIdx.y, b = blockIdx.z;
    const int qlen = q_len[b], vlen = v_len[b];
    const int bh = b * NB_HEAD + hh;

    if (q0 >= qlen) {
        const int row = t >> 1, cs = (t & 1) * 32;
        float* o = out + ((size_t)b * SEQ + q0 + row) * D_MODEL + hh * HEAD_DIM + cs;
        const float4 z = make_float4(0.f, 0.f, 0.f, 0.f);
        #pragma unroll
        for (int u = 0; u < 8; ++u) *(float4*)(o + u * 4) = z;
        return;
    }

    const size_t koff = (size_t)bh * SEQ * HEAD_DIM;
    const int qbase = q0 + wq * 32;

    bf16x8 qh[2][2], ql[2][2];
    #pragma unroll
    for (int s = 0; s < 2; ++s) {
        #pragma unroll
        for (int ks = 0; ks < 2; ++ks) {
            const size_t a = koff + (size_t)(qbase + s * 16 + li) * HEAD_DIM + ks * 32 + grp * 8;
            qh[s][ks] = *(const bf16x8*)(qhi + a);
            ql[s][ks] = *(const bf16x8*)(qlo + a);
        }
    }

    f32x4 O[2][4] = {};
    float m_s[2][4], l_s[2][4];
    #pragma unroll
    for (int s = 0; s < 2; ++s)
        #pragma unroll
        for (int r = 0; r < 4; ++r) { m_s[s][r] = -1e30f; l_s[s][r] = 0.f; }

    const int srow = t >> 3, cpos = t & 7;
    const int nkt = (vlen + 63) >> 6;

    for (int tt = 0; tt < nkt; ++tt) {
        const int k0 = tt * 64;
        __syncthreads();

        #pragma unroll
        for (int h2 = 0; h2 < 2; ++h2) {
            const int r = h2 * 32 + srow;
            const int c = cpos ^ (r & 7);
            const size_t gk = koff + (size_t)(k0 + r) * HEAD_DIM + c * 8;
            const size_t gv = ((size_t)bh * HEAD_DIM + r) * SEQ + k0 + c * 8;
            const int dst = h2 * 2048 + t * 8;
            __builtin_amdgcn_global_load_lds(
                (const __attribute__((address_space(1))) void*)(khi + gk),
                (__attribute__((address_space(3))) void*)&Khi[dst], 16, 0, 0);
            __builtin_amdgcn_global_load_lds(
                (const __attribute__((address_space(1))) void*)(klo + gk),
                (__attribute__((address_space(3))) void*)&Klo[dst], 16, 0, 0);
            __builtin_amdgcn_global_load_lds(
                (const __attribute__((address_space(1))) void*)(vthi + gv),
                (__attribute__((address_space(3))) void*)&Vhi[dst], 16, 0, 0);
            __builtin_amdgcn_global_load_lds(
                (const __attribute__((address_space(1))) void*)(vtlo + gv),
                (__attribute__((address_space(3))) void*)&Vlo[dst], 16, 0, 0);
        }
        __syncthreads();

        f32x4 sacc[2][4] = {};
        #pragma unroll
        for (int ks = 0; ks < 2; ++ks) {
            #pragma unroll
            for (int j = 0; j < 4; ++j) {
                const int off = (j * 16 + li) * 64 + (((ks * 4 + grp) ^ (li & 7)) * 8);
                const bf16x8 kh_ = *(const bf16x8*)&Khi[off];
                const bf16x8 kl_ = *(const bf16x8*)&Klo[off];
                #pragma unroll
                for (int s = 0; s < 2; ++s) {
                    sacc[s][j] = __builtin_amdgcn_mfma_f32_16x16x32_bf16(qh[s][ks], kh_, sacc[s][j], 0, 0, 0);
                    sacc[s][j] = __builtin_amdgcn_mfma_f32_16x16x32_bf16(qh[s][ks], kl_, sacc[s][j], 0, 0, 0);
                    sacc[s][j] = __builtin_amdgcn_mfma_f32_16x16x32_bf16(ql[s][ks], kh_, sacc[s][j], 0, 0, 0);
                }
            }
        }

        #pragma unroll
        for (int s = 0; s < 2; ++s) {
            float mx[4] = {-1e30f, -1e30f, -1e30f, -1e30f};
            #pragma unroll
            for (int j = 0; j < 4; ++j) {
                const int key = k0 + j * 16 + li;
                #pragma unroll
                for (int r = 0; r < 4; ++r) {
                    float v = sacc[s][j][r] * 0.125f;
                    if (key >= vlen) v = -1e30f;
                    sacc[s][j][r] = v;
                    mx[r] = fmaxf(mx[r], v);
                }
            }
            #pragma unroll
            for (int r = 0; r < 4; ++r) {
                mx[r] = fmaxf(mx[r], __shfl_xor(mx[r], 1));
                mx[r] = fmaxf(mx[r], __shfl_xor(mx[r], 2));
                mx[r] = fmaxf(mx[r], __shfl_xor(mx[r], 4));
                mx[r] = fmaxf(mx[r], __shfl_xor(mx[r], 8));
            }
            float al[4], sum[4];
            #pragma unroll
            for (int r = 0; r < 4; ++r) {
                const float mn = fmaxf(m_s[s][r], mx[r]);
                al[r] = __expf(m_s[s][r] - mn);
                m_s[s][r] = mn;
                sum[r] = 0.f;
            }
            #pragma unroll
            for (int j = 0; j < 4; ++j) {
                #pragma unroll
                for (int r = 0; r < 4; ++r) {
                    const float p = __expf(sacc[s][j][r] - m_s[s][r]);
                    const __bf16 pb = (__bf16)p;
                    sum[r] += (float)pb;
                    Ps[wq * 32 + s * 16 + grp * 4 + r][j * 16 + li] = pb;
                }
            }
            #pragma unroll
            for (int r = 0; r < 4; ++r) {
                sum[r] += __shfl_xor(sum[r], 1);
                sum[r] += __shfl_xor(sum[r], 2);
                sum[r] += __shfl_xor(sum[r], 4);
                sum[r] += __shfl_xor(sum[r], 8);
                l_s[s][r] = l_s[s][r] * al[r] + sum[r];
            }
            #pragma unroll
            for (int j = 0; j < 4; ++j)
                #pragma unroll
                for (int r = 0; r < 4; ++r) O[s][j][r] *= al[r];
        }
        asm volatile("s_waitcnt lgkmcnt(0)" ::: "memory");

        #pragma unroll
        for (int ks = 0; ks < 2; ++ks) {
            bf16x8 pa[2];
            #pragma unroll
            for (int s = 0; s < 2; ++s)
                pa[s] = *(const bf16x8*)&Ps[wq * 32 + s * 16 + li][ks * 32 + grp * 8];
            #pragma unroll
            for (int j = 0; j < 4; ++j) {
                const int off = (j * 16 + li) * 64 + (((ks * 4 + grp) ^ (li & 7)) * 8);
                const bf16x8 vh_ = *(const bf16x8*)&Vhi[off];
                const bf16x8 vl_ = *(const bf16x8*)&Vlo[off];
                #pragma unroll
                for (int s = 0; s < 2; ++s) {
                    O[s][j] = __builtin_amdgcn_mfma_f32_16x16x32_bf16(pa[s], vh_, O[s][j], 0, 0, 0);
                    O[s][j] = __builtin_amdgcn_mfma_f32_16x16x32_bf16(pa[s], vl_, O[s][j], 0, 0, 0);
                }
            }
        }
    }

    #pragma unroll
    for (int s = 0; s < 2; ++s) {
        #pragma unroll
        for (int r = 0; r < 4; ++r) {
            const int q = qbase + s * 16 + grp * 4 + r;
            const float inv = (q < qlen) ? 1.f / l_s[s][r] : 0.f;
            #pragma unroll
            for (int j = 0; j < 4; ++j)
                out[((size_t)b * SEQ + q) * D_MODEL + hh * HEAD_DIM + j * 16 + li] = O[s][j][r] * inv;
        }
    }
}

extern "C" void kernel_launch(void* const* d_in, const int* in_sizes, int n_in,
                              void* d_out, int out_size, void* d_ws, size_t ws_size,
                              hipStream_t stream)
{
    (void)in_sizes; (void)n_in; (void)out_size; (void)ws_size;
    const float* Q_seq = (const float*)d_in[0];
    const float* K_seq = (const float*)d_in[1];
    const float* V_seq = (const float*)d_in[2];
    const int*   q_len = (const int*)d_in[3];
    const int*   v_len = (const int*)d_in[4];
    const float* WQ    = (const float*)d_in[5];
    const float* WK    = (const float*)d_in[6];
    const float* WV    = (const float*)d_in[7];
    float* out = (float*)d_out;

    // Workspace (__bf16 elems): wt 2x3M, x 2x12M, q/k 4x4M, vt 2x4M = 54M = 108 MB
    __bf16* wthi = (__bf16*)d_ws;
    __bf16* wtlo = wthi + 3 * WELEMS;
    __bf16* xhi_ = wtlo + 3 * WELEMS;
    __bf16* xlo_ = xhi_ + 3 * XELEMS;
    __bf16* qhi_ = xlo_ + 3 * XELEMS;
    __bf16* qlo_ = qhi_ + XELEMS;
    __bf16* khi_ = qlo_ + XELEMS;
    __bf16* klo_ = khi_ + XELEMS;
    __bf16* vthi_ = klo_ + XELEMS;
    __bf16* vtlo_ = vthi_ + XELEMS;

    dim3 blk(256);

    dim3 cg(D_MODEL / 64, D_MODEL / 64, 3);     // (16,16,3)
    conv_wt_kernel<<<cg, blk, 0, stream>>>(WQ, WK, WV, wthi, wtlo);

    dim3 xg((unsigned)(XELEMS / 2048), 3);      // (2048,3)
    conv_x_kernel<<<xg, blk, 0, stream>>>(Q_seq, K_seq, V_seq, q_len, v_len, xhi_, xlo_);

    dim3 pg(D_MODEL / 128, MROWS / 128, 3);     // (8,32,3)
    proj_mfma_kernel<<<pg, blk, 0, stream>>>(xhi_, xlo_, wthi, wtlo, q_len, v_len,
                                             qhi_, qlo_, khi_, klo_, vthi_, vtlo_);

    dim3 ag(SEQ / 128, NB_HEAD, BATCH);         // (16,16,2)
    attn_mfma_kernel<<<ag, blk, 0, stream>>>(qhi_, qlo_, khi_, klo_, vthi_, vtlo_,
                                             q_len, v_len, out);
}